// Round 4
// baseline (46763.840 us; speedup 1.0000x reference)
//
#include <hip/hip_runtime.h>

#define UNITS  2048
#define IDIM   512
#define TSTEPS 8192

typedef float        v4f __attribute__((ext_vector_type(4)));
typedef float        v2f __attribute__((ext_vector_type(2)));
typedef unsigned int v4u __attribute__((ext_vector_type(4)));

__device__ __forceinline__ float ftanh(float s) {
    // tanh(s) = 1 - 2/(e^{2s}+1);  e^{2s} = 2^{s*2*log2(e)}
    float z = __builtin_amdgcn_exp2f(s * 2.885390081777927f);
    return 1.0f - 2.0f * __builtin_amdgcn_rcpf(z + 1.0f);
}

__device__ __forceinline__ float dot4(float4 a, float4 b) {
    return a.x * b.x + a.y * b.y + a.z * b.z + a.w * b.w;
}

// ---- flag primitives: atomics execute in the XCD-local L2 (TCC) — coherent
// ---- across all CUs of one XCD irrespective of L1 state. sc0 on atomic = return old.
__device__ __forceinline__ unsigned poll_flag(const unsigned* p) {
    unsigned old;
    unsigned zero = 0u;
    asm volatile("global_atomic_or %0, %1, %2, off sc0\n\t"
                 "s_waitcnt vmcnt(0)"
                 : "=v"(old) : "v"(p), "v"(zero) : "memory");
    return old;
}
__device__ __forceinline__ void flag_add(unsigned* p) {
    unsigned one = 1u;
    asm volatile("global_atomic_add %0, %1, off"
                 :: "v"(p), "v"(one) : "memory");
}

// ---- device-scope primitives (fallback kernel, proven in Round 2) ----
__device__ __forceinline__ bool bad4(v4f v) {
    v4u u = __builtin_bit_cast(v4u, v);
    bool b = false;
#pragma unroll
    for (int i = 0; i < 4; ++i) b |= (u[i] == 0u) | (u[i] == 0xAAAAAAAAu);
    return b;
}
__device__ __forceinline__ v4f poll_load_dev(const float4* p) {
    v4f v;
    asm volatile("global_load_dwordx4 %0, %1, off sc1\n\t"
                 "s_waitcnt vmcnt(0)"
                 : "=v"(v) : "v"(p) : "memory");
    return v;
}
__device__ __forceinline__ void pub_store_dev(float4* p, v4f v) {
    asm volatile("global_store_dwordx4 %0, %1, off sc1"
                 :: "v"(p), "v"(v) : "memory");
}

// =======================================================================
// Kernel 0: zero claim counter + per-step flag array at head of d_ws
// layout (ints): ws[0] = claim counter; ws[64 .. 64+8192) = flags[t]
// =======================================================================
__global__ void zero_ws(int* ws) {
    int i = blockIdx.x * 256 + threadIdx.x;
    if (i < 64 + TSTEPS) ws[i] = 0;
}

// =======================================================================
// Kernel 1: xin[t][u] = sum_k x[t][k]*wax[u][k] + ba[u]   (8192 x 2048)
// =======================================================================
#define GT 64
#define GU 64
#define GK 32
__global__ __launch_bounds__(256)
void xin_gemm(const float* __restrict__ x,    // (T, 512)
              const float* __restrict__ wax,  // (U, 512)
              const float* __restrict__ ba,   // (U)
              float* __restrict__ xin)        // (T, U)
{
    __shared__ float Xs[GT][GK + 4];
    __shared__ float Ws[GU][GK + 4];
    const int tid = threadIdx.x;
    const int tx = tid & 15, ty = tid >> 4;
    const int t0 = blockIdx.x * GT, u0 = blockIdx.y * GU;
    float acc[4][4] = {};
    const float4* x4 = (const float4*)x;
    const float4* w4 = (const float4*)wax;
    const int tr = tid >> 2;        // 0..63
    const int kq = tid & 3;         // 0..3

    for (int k0 = 0; k0 < IDIM; k0 += GK) {
        float4 a0 = x4[(size_t)(t0 + tr) * 128 + (k0 >> 2) + kq * 2];
        float4 a1 = x4[(size_t)(t0 + tr) * 128 + (k0 >> 2) + kq * 2 + 1];
        float4 b0 = w4[(size_t)(u0 + tr) * 128 + (k0 >> 2) + kq * 2];
        float4 b1 = w4[(size_t)(u0 + tr) * 128 + (k0 >> 2) + kq * 2 + 1];
        __syncthreads();            // protect previous iteration's LDS reads
        *(float4*)&Xs[tr][kq * 8]     = a0;
        *(float4*)&Xs[tr][kq * 8 + 4] = a1;
        *(float4*)&Ws[tr][kq * 8]     = b0;
        *(float4*)&Ws[tr][kq * 8 + 4] = b1;
        __syncthreads();
#pragma unroll
        for (int k = 0; k < GK; k += 4) {
            float4 xv[4], wv[4];
#pragma unroll
            for (int i = 0; i < 4; ++i) xv[i] = *(float4*)&Xs[ty * 4 + i][k];
#pragma unroll
            for (int j = 0; j < 4; ++j) wv[j] = *(float4*)&Ws[tx * 4 + j][k];
#pragma unroll
            for (int i = 0; i < 4; ++i)
#pragma unroll
                for (int j = 0; j < 4; ++j)
                    acc[i][j] += dot4(xv[i], wv[j]);
        }
    }
    float4 bb = *(const float4*)&ba[u0 + tx * 4];
#pragma unroll
    for (int i = 0; i < 4; ++i) {
        float4 o;
        o.x = acc[i][0] + bb.x; o.y = acc[i][1] + bb.y;
        o.z = acc[i][2] + bb.z; o.w = acc[i][3] + bb.w;
        *(float4*)&xin[(size_t)(t0 + ty * 4 + i) * UNITS + u0 + tx * 4] = o;
    }
}

// =======================================================================
// Kernel 2: single-XCD persistent scan with L2-atomic flag sync.
// 32 workers on XCD0, 512 thr, 64 rows/block, 8 rows/wave
// (6 rows in VGPRs + 2 rows in LDS).  Data: plain st/ld via XCD0 L2.
// Release: st.data -> s_waitcnt vmcnt(0) -> atomic flag++ (same L2).
// Acquire: atomic poll flag==256 -> first-touch plain loads (L1 miss -> L2).
// =======================================================================
#define SCAN_LDS_BYTES ((16 * 576 + 576) * 16)   // 147456 + 9216 = 156672

__device__ __forceinline__ float fold2(float a, float b, int d, int lane) {
    float keep = (lane & d) ? b : a;
    float send = (lane & d) ? a : b;
    return keep + __shfl_xor(send, d, 64);
}

__global__ __launch_bounds__(512, 2)
void rnn_scan_xcd(const float* __restrict__ waa,
                  const float* __restrict__ xin,   // (T, U), precomputed
                  float* __restrict__ ys,          // (T, U) == d_out
                  int* __restrict__ cnt,
                  unsigned* __restrict__ flags)    // (T) step counters
{
    extern __shared__ float4 smem[];
    float4* lws  = smem;              // 16 padded rows x 576 float4
    float4* abuf = smem + 16 * 576;   // 576 float4

    __shared__ int s_slot;
    if (threadIdx.x == 0) {
        unsigned xcc;
        asm volatile("s_getreg_b32 %0, hwreg(HW_REG_XCC_ID)" : "=s"(xcc));
        s_slot = ((xcc & 0xf) == 0) ? atomicAdd(cnt, 1) : -1;   // claim a worker slot
    }
    __syncthreads();
    const int slot = s_slot;
    if (slot < 0 || slot >= 32) return;   // not a worker

    const int tid  = threadIdx.x;
    const int lane = tid & 63;
    const int wave = tid >> 6;
    const int r0   = slot * 64 + wave * 8;      // this wave's 8 rows

    const float4* waa4 = (const float4*)waa;    // (UNITS, 512) float4s
    // 6 register-resident rows (192 VGPRs of weights, live all 8192 steps)
    float4 w[6][8];
#pragma unroll
    for (int r = 0; r < 6; ++r)
#pragma unroll
        for (int k = 0; k < 8; ++k)
            w[r][k] = waa4[(size_t)(r0 + r) * 512 + lane * 8 + k];
    // 2 LDS-resident rows per wave, padded (f -> f + f/8): conflict-free b128
    float4* lw0 = &lws[(wave * 2 + 0) * 576];
    float4* lw1 = &lws[(wave * 2 + 1) * 576];
#pragma unroll
    for (int k = 0; k < 8; ++k) {
        lw0[lane * 9 + k] = waa4[(size_t)(r0 + 6) * 512 + lane * 8 + k];
        lw1[lane * 9 + k] = waa4[(size_t)(r0 + 7) * 512 + lane * 8 + k];
    }
    __syncthreads();

    int budget = 1 << 22;   // sticky safety valve: pathology -> visible fail, not hang

    for (int t = 0; t < TSTEPS; ++t) {
        float xv = xin[(size_t)t * UNITS + r0 + (lane & 7)];
        float out;
        if (t == 0) {
            out = ftanh(xv);            // a0 = 0 => no matvec term
        } else {
            if (tid == 0) {             // single poller per block (L2 atomic)
                unsigned f = poll_flag(&flags[t - 1]);
                while (f < 256u && --budget > 0) f = poll_flag(&flags[t - 1]);
            }
            __syncthreads();            // B1: flag observed; also fences abuf reuse

            // first touch of ys[t-1] lines AFTER the flag => L1 miss => fresh L2 data
            const float4* src = (const float4*)(ys + (size_t)(t - 1) * UNITS) + tid;
            float4 av = *src;
            abuf[tid + (tid >> 3)] = av;
            __syncthreads();            // B2: staging visible block-wide

            // 8-row matvec partials, packed fp32 (v_pk_fma_f32)
            v2f acc2[8];
#pragma unroll
            for (int r = 0; r < 8; ++r) acc2[r] = (v2f){0.f, 0.f};
            const float4* ab = &abuf[lane * 9];
            const float4* l0 = &lw0[lane * 9];
            const float4* l1 = &lw1[lane * 9];
#pragma unroll
            for (int k = 0; k < 8; ++k) {
                float4 a4 = ab[k];
                v2f alo = {a4.x, a4.y}, ahi = {a4.z, a4.w};
#pragma unroll
                for (int r = 0; r < 6; ++r) {
                    v2f wlo = {w[r][k].x, w[r][k].y};
                    v2f whi = {w[r][k].z, w[r][k].w};
                    acc2[r] += alo * wlo;
                    acc2[r] += ahi * whi;
                }
                float4 u0 = l0[k], u1 = l1[k];
                acc2[6] += alo * (v2f){u0.x, u0.y};
                acc2[6] += ahi * (v2f){u0.z, u0.w};
                acc2[7] += alo * (v2f){u1.x, u1.y};
                acc2[7] += ahi * (v2f){u1.z, u1.w};
            }
            float acc[8];
#pragma unroll
            for (int r = 0; r < 8; ++r) acc[r] = acc2[r].x + acc2[r].y;

            // 8-row wave reduction: 3 fold rounds -> lane holds row (lane&7)
            float f4[4], f2[2], f1;
#pragma unroll
            for (int r = 0; r < 4; ++r) f4[r] = fold2(acc[2 * r], acc[2 * r + 1], 1, lane);
#pragma unroll
            for (int r = 0; r < 2; ++r) f2[r] = fold2(f4[2 * r], f4[2 * r + 1], 2, lane);
            f1 = fold2(f2[0], f2[1], 4, lane);
            f1 += __shfl_xor(f1, 8, 64);
            f1 += __shfl_xor(f1, 16, 64);
            f1 += __shfl_xor(f1, 32, 64);
            out = ftanh(f1 + xv);
        }
        if (lane < 8)
            ys[(size_t)t * UNITS + r0 + lane] = out;     // plain write-through store
        asm volatile("s_waitcnt vmcnt(0)" ::: "memory"); // release: data in L2 first
        if (lane == 0)
            flag_add(&flags[t]);                          // then publish readiness
    }
}

// =======================================================================
// Fallback (Round-2 kernel, device-scope sync): used only if ws too small
// =======================================================================
__global__ __launch_bounds__(512, 2)
void rnn_scan_fb(const float* __restrict__ x,
                 const float* __restrict__ waa,
                 const float* __restrict__ wax,
                 const float* __restrict__ ba,
                 float* __restrict__ ys)
{
    __shared__ float4 fabuf[2][576];
    const int tid  = threadIdx.x;
    const int lane = tid & 63;
    const int wave = tid >> 6;
    const int r0   = blockIdx.x * 32 + wave * 4;

    const float4* waa4 = (const float4*)waa;
    const float4* wax4 = (const float4*)wax;
    float4 w[4][8]; float4 wx[4][2]; float bav[4];
#pragma unroll
    for (int r = 0; r < 4; ++r) {
#pragma unroll
        for (int k = 0; k < 8; ++k) w[r][k] = waa4[(size_t)(r0 + r) * 512 + lane * 8 + k];
#pragma unroll
        for (int k = 0; k < 2; ++k) wx[r][k] = wax4[(size_t)(r0 + r) * 128 + lane * 2 + k];
        bav[r] = ba[r0 + r];
    }
    const float4* x4 = (const float4*)x;
    int budget = 1 << 22;

    for (int t = 0; t < TSTEPS; ++t) {
        float4 xa = x4[(size_t)t * 128 + lane * 2];
        float4 xb = x4[(size_t)t * 128 + lane * 2 + 1];
        if (t > 0) {
            const float4* src = (const float4*)(ys + (size_t)(t - 1) * UNITS) + tid;
            v4f av = poll_load_dev(src);
            while (bad4(av) && --budget > 0) av = poll_load_dev(src);
            fabuf[t & 1][tid + (tid >> 3)] = *(const float4*)&av;
        }
        float s[4];
#pragma unroll
        for (int r = 0; r < 4; ++r)
            s[r] = dot4(xa, wx[r][0]) + dot4(xb, wx[r][1]);
        if (t > 0) {
            __syncthreads();
            const float4* ab = &fabuf[t & 1][lane * 9];
#pragma unroll
            for (int k = 0; k < 8; ++k) {
                float4 av = ab[k];
#pragma unroll
                for (int r = 0; r < 4; ++r) s[r] += dot4(av, w[r][k]);
            }
        }
#pragma unroll
        for (int m = 32; m >= 1; m >>= 1)
#pragma unroll
            for (int r = 0; r < 4; ++r) s[r] += __shfl_xor(s[r], m, 64);
        if (lane == 0) {
            v4f o;
#pragma unroll
            for (int r = 0; r < 4; ++r) o[r] = ftanh(s[r] + bav[r]);
            pub_store_dev((float4*)(ys + (size_t)t * UNITS + r0), o);
        }
    }
}

extern "C" void kernel_launch(void* const* d_in, const int* in_sizes, int n_in,
                              void* d_out, int out_size, void* d_ws, size_t ws_size,
                              hipStream_t stream) {
    const float* x   = (const float*)d_in[0];   // (1, 8192, 512)
    const float* waa = (const float*)d_in[1];   // (2048, 2048)
    const float* wax = (const float*)d_in[2];   // (2048, 512)
    const float* ba  = (const float*)d_in[3];   // (2048, 1)
    float* ys = (float*)d_out;                  // (1, 8192, 2048)

    // ws layout: [0]=claim cnt, [64..64+8192) flags, then xin (16B aligned)
    const size_t xin_off = ((64 + TSTEPS) * sizeof(int) + 255) & ~(size_t)255;
    const size_t need = xin_off + (size_t)TSTEPS * UNITS * sizeof(float);
    if (ws_size >= need) {
        (void)hipFuncSetAttribute(reinterpret_cast<const void*>(rnn_scan_xcd),
                                  hipFuncAttributeMaxDynamicSharedMemorySize,
                                  SCAN_LDS_BYTES);
        int*      wsi   = (int*)d_ws;
        unsigned* flags = (unsigned*)d_ws + 64;
        float*    xin   = (float*)((char*)d_ws + xin_off);
        hipLaunchKernelGGL(zero_ws, dim3((64 + TSTEPS + 255) / 256), dim3(256), 0, stream, wsi);
        hipLaunchKernelGGL(xin_gemm, dim3(TSTEPS / GT, UNITS / GU), dim3(256), 0, stream,
                           x, wax, ba, xin);
        hipLaunchKernelGGL(rnn_scan_xcd, dim3(1024), dim3(512), SCAN_LDS_BYTES, stream,
                           waa, xin, ys, wsi, flags);
    } else {
        hipLaunchKernelGGL(rnn_scan_fb, dim3(64), dim3(512), 0, stream,
                           x, waa, wax, ba, ys);
    }
}

// Round 5
// 20200.302 us; speedup vs baseline: 2.3150x; 2.3150x over previous
//
#include <hip/hip_runtime.h>

#define UNITS  2048
#define IDIM   512
#define TSTEPS 8192

typedef float        v4f __attribute__((ext_vector_type(4)));
typedef float        v2f __attribute__((ext_vector_type(2)));
typedef unsigned int v4u __attribute__((ext_vector_type(4)));

__device__ __forceinline__ float ftanh(float s) {
    // tanh(s) = 1 - 2/(e^{2s}+1);  e^{2s} = 2^{s*2*log2(e)}
    float z = __builtin_amdgcn_exp2f(s * 2.885390081777927f);
    return 1.0f - 2.0f * __builtin_amdgcn_rcpf(z + 1.0f);
}

__device__ __forceinline__ float dot4(float4 a, float4 b) {
    return a.x * b.x + a.y * b.y + a.z * b.z + a.w * b.w;
}

// ---- flag primitives: atomics execute in the XCD-local L2 (TCC) — coherent
// ---- across all CUs of one XCD irrespective of L1 state. sc0 on atomic = return old.
__device__ __forceinline__ unsigned poll_flag(const unsigned* p) {
    unsigned old;
    unsigned zero = 0u;
    asm volatile("global_atomic_or %0, %1, %2, off sc0\n\t"
                 "s_waitcnt vmcnt(0)"
                 : "=v"(old) : "v"(p), "v"(zero) : "memory");
    return old;
}
__device__ __forceinline__ void flag_add(unsigned* p) {
    unsigned one = 1u;
    asm volatile("global_atomic_add %0, %1, off"
                 :: "v"(p), "v"(one) : "memory");
}

// ---- device-scope primitives (fallback kernel, proven in Round 2) ----
__device__ __forceinline__ bool bad4(v4f v) {
    v4u u = __builtin_bit_cast(v4u, v);
    bool b = false;
#pragma unroll
    for (int i = 0; i < 4; ++i) b |= (u[i] == 0u) | (u[i] == 0xAAAAAAAAu);
    return b;
}
__device__ __forceinline__ v4f poll_load_dev(const float4* p) {
    v4f v;
    asm volatile("global_load_dwordx4 %0, %1, off sc1\n\t"
                 "s_waitcnt vmcnt(0)"
                 : "=v"(v) : "v"(p) : "memory");
    return v;
}
__device__ __forceinline__ void pub_store_dev(float4* p, v4f v) {
    asm volatile("global_store_dwordx4 %0, %1, off sc1"
                 :: "v"(p), "v"(v) : "memory");
}

// =======================================================================
// ws layout (u32 index): [0] claim cnt; [64..64+256) flags: 8 slots x 32
// stride (one 128B line per slot, monotone counters); xin at byte 2048.
// =======================================================================
__global__ void zero_ws(int* ws) {
    int i = threadIdx.x;
    if (i < 512) ws[i] = 0;
}

// =======================================================================
// Kernel 1: xin[t][u] = sum_k x[t][k]*wax[u][k] + ba[u]   (8192 x 2048)
// =======================================================================
#define GT 64
#define GU 64
#define GK 32
__global__ __launch_bounds__(256)
void xin_gemm(const float* __restrict__ x,    // (T, 512)
              const float* __restrict__ wax,  // (U, 512)
              const float* __restrict__ ba,   // (U)
              float* __restrict__ xin)        // (T, U)
{
    __shared__ float Xs[GT][GK + 4];
    __shared__ float Ws[GU][GK + 4];
    const int tid = threadIdx.x;
    const int tx = tid & 15, ty = tid >> 4;
    const int t0 = blockIdx.x * GT, u0 = blockIdx.y * GU;
    float acc[4][4] = {};
    const float4* x4 = (const float4*)x;
    const float4* w4 = (const float4*)wax;
    const int tr = tid >> 2;        // 0..63
    const int kq = tid & 3;         // 0..3

    for (int k0 = 0; k0 < IDIM; k0 += GK) {
        float4 a0 = x4[(size_t)(t0 + tr) * 128 + (k0 >> 2) + kq * 2];
        float4 a1 = x4[(size_t)(t0 + tr) * 128 + (k0 >> 2) + kq * 2 + 1];
        float4 b0 = w4[(size_t)(u0 + tr) * 128 + (k0 >> 2) + kq * 2];
        float4 b1 = w4[(size_t)(u0 + tr) * 128 + (k0 >> 2) + kq * 2 + 1];
        __syncthreads();            // protect previous iteration's LDS reads
        *(float4*)&Xs[tr][kq * 8]     = a0;
        *(float4*)&Xs[tr][kq * 8 + 4] = a1;
        *(float4*)&Ws[tr][kq * 8]     = b0;
        *(float4*)&Ws[tr][kq * 8 + 4] = b1;
        __syncthreads();
#pragma unroll
        for (int k = 0; k < GK; k += 4) {
            float4 xv[4], wv[4];
#pragma unroll
            for (int i = 0; i < 4; ++i) xv[i] = *(float4*)&Xs[ty * 4 + i][k];
#pragma unroll
            for (int j = 0; j < 4; ++j) wv[j] = *(float4*)&Ws[tx * 4 + j][k];
#pragma unroll
            for (int i = 0; i < 4; ++i)
#pragma unroll
                for (int j = 0; j < 4; ++j)
                    acc[i][j] += dot4(xv[i], wv[j]);
        }
    }
    float4 bb = *(const float4*)&ba[u0 + tx * 4];
#pragma unroll
    for (int i = 0; i < 4; ++i) {
        float4 o;
        o.x = acc[i][0] + bb.x; o.y = acc[i][1] + bb.y;
        o.z = acc[i][2] + bb.z; o.w = acc[i][3] + bb.w;
        *(float4*)&xin[(size_t)(t0 + ty * 4 + i) * UNITS + u0 + tx * 4] = o;
    }
}

// =======================================================================
// Kernel 2: single-XCD persistent scan, L2-atomic flag sync (low-contention):
//  - release: lane<8 stores -> vmcnt(0) -> __syncthreads -> ONE flag_add/block
//  - flags: 8 rotating slots, one 128B line each, monotone (no zeroing)
//  - acquire: tid0 polls slot (t-1)&7 for 32*((t-1)/8+1), s_sleep backoff
//  - data: plain loads, first touch after flag => L1 miss => fresh L2 line
// =======================================================================
#define SCAN_LDS_BYTES ((16 * 576 + 576) * 16)   // 147456 + 9216 = 156672

__device__ __forceinline__ float fold2(float a, float b, int d, int lane) {
    float keep = (lane & d) ? b : a;
    float send = (lane & d) ? a : b;
    return keep + __shfl_xor(send, d, 64);
}

__global__ __launch_bounds__(512, 2)
void rnn_scan_xcd(const float* __restrict__ waa,
                  const float* __restrict__ xin,   // (T, U), precomputed
                  float* __restrict__ ys,          // (T, U) == d_out
                  int* __restrict__ cnt,
                  unsigned* __restrict__ flags)    // 8 slots x 32-u32 stride
{
    extern __shared__ float4 smem[];
    float4* lws  = smem;              // 16 padded rows x 576 float4
    float4* abuf = smem + 16 * 576;   // 576 float4

    __shared__ int s_slot;
    if (threadIdx.x == 0) {
        unsigned xcc;
        asm volatile("s_getreg_b32 %0, hwreg(HW_REG_XCC_ID)" : "=s"(xcc));
        s_slot = ((xcc & 0xf) == 0) ? atomicAdd(cnt, 1) : -1;   // claim a worker slot
    }
    __syncthreads();
    const int slot = s_slot;
    if (slot < 0 || slot >= 32) return;   // not a worker

    const int tid  = threadIdx.x;
    const int lane = tid & 63;
    const int wave = tid >> 6;
    const int r0   = slot * 64 + wave * 8;      // this wave's 8 rows

    const float4* waa4 = (const float4*)waa;    // (UNITS, 512) float4s
    // 6 register-resident rows (192 regs of weights, live all 8192 steps)
    float4 w[6][8];
#pragma unroll
    for (int r = 0; r < 6; ++r)
#pragma unroll
        for (int k = 0; k < 8; ++k)
            w[r][k] = waa4[(size_t)(r0 + r) * 512 + lane * 8 + k];
    // 2 LDS-resident rows per wave, padded (f -> f + f/8): conflict-free b128
    float4* lw0 = &lws[(wave * 2 + 0) * 576];
    float4* lw1 = &lws[(wave * 2 + 1) * 576];
#pragma unroll
    for (int k = 0; k < 8; ++k) {
        lw0[lane * 9 + k] = waa4[(size_t)(r0 + 6) * 512 + lane * 8 + k];
        lw1[lane * 9 + k] = waa4[(size_t)(r0 + 7) * 512 + lane * 8 + k];
    }
    __syncthreads();

    int budget = 1 << 22;   // sticky safety valve: pathology -> visible fail, not hang

    for (int t = 0; t < TSTEPS; ++t) {
        float xv = xin[(size_t)t * UNITS + r0 + (lane & 7)];   // issued early
        float out;
        if (t == 0) {
            out = ftanh(xv);            // a0 = 0 => no matvec term
        } else {
            if (tid == 0) {             // single poller per block, dedicated line
                const unsigned tgt = 32u * (((unsigned)(t - 1) >> 3) + 1u);
                unsigned* fp = &flags[((t - 1) & 7) * 32];
                unsigned f = poll_flag(fp);
                while (f < tgt && --budget > 0) {
                    __builtin_amdgcn_s_sleep(1);   // ~64 cyc backoff off the hot line
                    f = poll_flag(fp);
                }
            }
            __syncthreads();            // B1: flag observed by whole block

            // first touch of ys[t-1] lines AFTER the flag => L1 miss => fresh L2 data
            const float4* src = (const float4*)(ys + (size_t)(t - 1) * UNITS) + tid;
            float4 av = *src;
            abuf[tid + (tid >> 3)] = av;
            __syncthreads();            // B2: staging visible block-wide

            // 8-row matvec partials, packed fp32 (v_pk_fma_f32)
            v2f acc2[8];
#pragma unroll
            for (int r = 0; r < 8; ++r) acc2[r] = (v2f){0.f, 0.f};
            const float4* ab = &abuf[lane * 9];
            const float4* l0 = &lw0[lane * 9];
            const float4* l1 = &lw1[lane * 9];
#pragma unroll
            for (int k = 0; k < 8; ++k) {
                float4 a4 = ab[k];
                v2f alo = {a4.x, a4.y}, ahi = {a4.z, a4.w};
#pragma unroll
                for (int r = 0; r < 6; ++r) {
                    v2f wlo = {w[r][k].x, w[r][k].y};
                    v2f whi = {w[r][k].z, w[r][k].w};
                    acc2[r] += alo * wlo;
                    acc2[r] += ahi * whi;
                }
                float4 u0 = l0[k], u1 = l1[k];
                acc2[6] += alo * (v2f){u0.x, u0.y};
                acc2[6] += ahi * (v2f){u0.z, u0.w};
                acc2[7] += alo * (v2f){u1.x, u1.y};
                acc2[7] += ahi * (v2f){u1.z, u1.w};
            }
            float acc[8];
#pragma unroll
            for (int r = 0; r < 8; ++r) acc[r] = acc2[r].x + acc2[r].y;

            // 8-row wave reduction: 3 fold rounds -> lane holds row (lane&7)
            float f4[4], f2[2], f1;
#pragma unroll
            for (int r = 0; r < 4; ++r) f4[r] = fold2(acc[2 * r], acc[2 * r + 1], 1, lane);
#pragma unroll
            for (int r = 0; r < 2; ++r) f2[r] = fold2(f4[2 * r], f4[2 * r + 1], 2, lane);
            f1 = fold2(f2[0], f2[1], 4, lane);
            f1 += __shfl_xor(f1, 8, 64);
            f1 += __shfl_xor(f1, 16, 64);
            f1 += __shfl_xor(f1, 32, 64);
            out = ftanh(f1 + xv);
        }
        if (lane < 8)
            ys[(size_t)t * UNITS + r0 + lane] = out;     // plain write-through store
        asm volatile("s_waitcnt vmcnt(0)" ::: "memory"); // per-wave: data in L2
        __syncthreads();                                 // B3: all 8 waves drained
        if (tid == 0)
            flag_add(&flags[(t & 7) * 32]);              // ONE add per block per step
    }
}

// =======================================================================
// Fallback (Round-2 kernel, device-scope sync): used only if ws too small
// =======================================================================
__global__ __launch_bounds__(512, 2)
void rnn_scan_fb(const float* __restrict__ x,
                 const float* __restrict__ waa,
                 const float* __restrict__ wax,
                 const float* __restrict__ ba,
                 float* __restrict__ ys)
{
    __shared__ float4 fabuf[2][576];
    const int tid  = threadIdx.x;
    const int lane = tid & 63;
    const int wave = tid >> 6;
    const int r0   = blockIdx.x * 32 + wave * 4;

    const float4* waa4 = (const float4*)waa;
    const float4* wax4 = (const float4*)wax;
    float4 w[4][8]; float4 wx[4][2]; float bav[4];
#pragma unroll
    for (int r = 0; r < 4; ++r) {
#pragma unroll
        for (int k = 0; k < 8; ++k) w[r][k] = waa4[(size_t)(r0 + r) * 512 + lane * 8 + k];
#pragma unroll
        for (int k = 0; k < 2; ++k) wx[r][k] = wax4[(size_t)(r0 + r) * 128 + lane * 2 + k];
        bav[r] = ba[r0 + r];
    }
    const float4* x4 = (const float4*)x;
    int budget = 1 << 22;

    for (int t = 0; t < TSTEPS; ++t) {
        float4 xa = x4[(size_t)t * 128 + lane * 2];
        float4 xb = x4[(size_t)t * 128 + lane * 2 + 1];
        if (t > 0) {
            const float4* src = (const float4*)(ys + (size_t)(t - 1) * UNITS) + tid;
            v4f av = poll_load_dev(src);
            while (bad4(av) && --budget > 0) av = poll_load_dev(src);
            fabuf[t & 1][tid + (tid >> 3)] = *(const float4*)&av;
        }
        float s[4];
#pragma unroll
        for (int r = 0; r < 4; ++r)
            s[r] = dot4(xa, wx[r][0]) + dot4(xb, wx[r][1]);
        if (t > 0) {
            __syncthreads();
            const float4* ab = &fabuf[t & 1][lane * 9];
#pragma unroll
            for (int k = 0; k < 8; ++k) {
                float4 av = ab[k];
#pragma unroll
                for (int r = 0; r < 4; ++r) s[r] += dot4(av, w[r][k]);
            }
        }
#pragma unroll
        for (int m = 32; m >= 1; m >>= 1)
#pragma unroll
            for (int r = 0; r < 4; ++r) s[r] += __shfl_xor(s[r], m, 64);
        if (lane == 0) {
            v4f o;
#pragma unroll
            for (int r = 0; r < 4; ++r) o[r] = ftanh(s[r] + bav[r]);
            pub_store_dev((float4*)(ys + (size_t)t * UNITS + r0), o);
        }
    }
}

extern "C" void kernel_launch(void* const* d_in, const int* in_sizes, int n_in,
                              void* d_out, int out_size, void* d_ws, size_t ws_size,
                              hipStream_t stream) {
    const float* x   = (const float*)d_in[0];   // (1, 8192, 512)
    const float* waa = (const float*)d_in[1];   // (2048, 2048)
    const float* wax = (const float*)d_in[2];   // (2048, 512)
    const float* ba  = (const float*)d_in[3];   // (2048, 1)
    float* ys = (float*)d_out;                  // (1, 8192, 2048)

    const size_t xin_off = 2048;                // bytes; after cnt + padded flags
    const size_t need = xin_off + (size_t)TSTEPS * UNITS * sizeof(float);
    if (ws_size >= need) {
        (void)hipFuncSetAttribute(reinterpret_cast<const void*>(rnn_scan_xcd),
                                  hipFuncAttributeMaxDynamicSharedMemorySize,
                                  SCAN_LDS_BYTES);
        int*      wsi   = (int*)d_ws;
        unsigned* flags = (unsigned*)d_ws + 64;
        float*    xin   = (float*)((char*)d_ws + xin_off);
        hipLaunchKernelGGL(zero_ws, dim3(1), dim3(512), 0, stream, wsi);
        hipLaunchKernelGGL(xin_gemm, dim3(TSTEPS / GT, UNITS / GU), dim3(256), 0, stream,
                           x, wax, ba, xin);
        hipLaunchKernelGGL(rnn_scan_xcd, dim3(1024), dim3(512), SCAN_LDS_BYTES, stream,
                           waa, xin, ys, wsi, flags);
    } else {
        hipLaunchKernelGGL(rnn_scan_fb, dim3(64), dim3(512), 0, stream,
                           x, waa, wax, ba, ys);
    }
}